// Round 2
// baseline (300.725 us; speedup 1.0000x reference)
//
#include <hip/hip_runtime.h>
#include <hip/hip_bf16.h>

#define HDIM 256
#define HPDIM 128

typedef short bf8 __attribute__((ext_vector_type(8)));   // 8 bf16 in 4 VGPRs
typedef float f32x4 __attribute__((ext_vector_type(4)));

__device__ inline short f2bf(float f) {
  union { float f; unsigned u; } v; v.f = f;
  unsigned r = (v.u + 0x7FFFu + ((v.u >> 16) & 1u)) >> 16;   // RNE
  return (short)(r & 0xFFFFu);
}

// ---------------- Kernel A: front MLP -> x3 (bf16) ----------------
// h = cc*h0 + (1-cc)*ht ; x1 = tanh(h @ fc1^T) ; x2 = tanh(x1 @ fc2^T)
// x3 = tanh(x2 @ fc3^T). One block per batch element, 128 threads.
__global__ __launch_bounds__(128) void k_mlp(
    const float* __restrict__ h0, const float* __restrict__ ht,
    const float* __restrict__ cp,
    const float* __restrict__ w1, const float* __restrict__ w2,
    const float* __restrict__ w3, short* __restrict__ x3bf) {
  __shared__ float hb[HDIM];
  __shared__ float x1[HPDIM];
  __shared__ float x2[HPDIM];
  const int b = blockIdx.x, t = threadIdx.x;
  float cc = cp[0]; cc = fminf(fmaxf(cc, 0.f), 1.f);
  hb[t]       = cc * h0[b*HDIM + t]       + (1.f - cc) * ht[b*HDIM + t];
  hb[t + 128] = cc * h0[b*HDIM + t + 128] + (1.f - cc) * ht[b*HDIM + t + 128];
  __syncthreads();
  float s = 0.f;
  const float4* wr = (const float4*)(w1 + t*HDIM);
  #pragma unroll 8
  for (int i = 0; i < 64; ++i) {
    float4 w = wr[i];
    s += hb[4*i]*w.x + hb[4*i+1]*w.y + hb[4*i+2]*w.z + hb[4*i+3]*w.w;
  }
  x1[t] = tanhf(s);
  __syncthreads();
  s = 0.f;
  wr = (const float4*)(w2 + t*HPDIM);
  #pragma unroll 8
  for (int i = 0; i < 32; ++i) {
    float4 w = wr[i];
    s += x1[4*i]*w.x + x1[4*i+1]*w.y + x1[4*i+2]*w.z + x1[4*i+3]*w.w;
  }
  x2[t] = tanhf(s);
  __syncthreads();
  s = 0.f;
  wr = (const float4*)(w3 + t*HPDIM);
  #pragma unroll 8
  for (int i = 0; i < 32; ++i) {
    float4 w = wr[i];
    s += x2[4*i]*w.x + x2[4*i+1]*w.y + x2[4*i+2]*w.z + x2[4*i+3]*w.w;
  }
  x3bf[b*HPDIM + t] = f2bf(tanhf(s));
}

// ---------------- Kernel B/C: fused hypernetwork GEMM ----------------
// PHASE 0: g1out[b,k] = tanh( sum_h wvec(=msg)[b,h] * (x3[b,:] . fc4[k*256+h,:]) )
// PHASE 1: out[b,o]   =       sum_k wvec(=g1)[b,k]  * (x3[b,:] . fc4[65536+o*256+k,:])
// Block = (kcol, btile of 256). 4 waves, each wave owns 64 b-rows.
// MFMA 16x16x32 bf16: A lane map A[m=lane&15][k=(lane>>4)*8+j],
//                     B lane map B[k=(lane>>4)*8+j][n=lane&15],
//                     D lane map D[row=(lane>>4)*4+reg][col=lane&15].
template<int PHASE>
__global__ __launch_bounds__(256) void k_hyper(
    const short* __restrict__ x3bf, const float* __restrict__ wvec,
    const float* __restrict__ fc4, float* __restrict__ g1out,
    float* __restrict__ out) {
  const int kcol = blockIdx.x;            // output column (k or o), 0..255
  const int wave = threadIdx.x >> 6;
  const int lane = threadIdx.x & 63;
  const int r16 = lane & 15, quad = lane >> 4;
  const int b0 = blockIdx.y * 256 + wave * 64;

  // A fragments: x3 rows for this wave's 64 b's, all K=128 (held in VGPRs)
  bf8 afr[4][4];
  #pragma unroll
  for (int bs = 0; bs < 4; ++bs)
    #pragma unroll
    for (int kc = 0; kc < 4; ++kc)
      afr[bs][kc] = *(const bf8*)(x3bf + (b0 + bs*16 + r16)*HPDIM + kc*32 + quad*8);

  float gacc[4][4];
  #pragma unroll
  for (int bs = 0; bs < 4; ++bs)
    #pragma unroll
    for (int i = 0; i < 4; ++i) gacc[bs][i] = 0.f;

  const size_t rbase = (PHASE ? (size_t)65536 : (size_t)0) + (size_t)kcol * 256;

  for (int ht = 0; ht < 16; ++ht) {       // 16 h-columns per iteration
    // B fragments: 16 fc4 rows (f32 -> bf16 on the fly). Lane reads 8
    // consecutive floats of row (rbase + ht*16 + r16) at col quad*8+kc*32.
    const float* rp = fc4 + (rbase + (size_t)(ht*16 + r16)) * HPDIM + quad*8;
    bf8 bfr[4];
    #pragma unroll
    for (int kc = 0; kc < 4; ++kc) {
      float4 p0 = *(const float4*)(rp + kc*32);
      float4 p1 = *(const float4*)(rp + kc*32 + 4);
      bf8 tt;
      tt[0]=f2bf(p0.x); tt[1]=f2bf(p0.y); tt[2]=f2bf(p0.z); tt[3]=f2bf(p0.w);
      tt[4]=f2bf(p1.x); tt[5]=f2bf(p1.y); tt[6]=f2bf(p1.z); tt[7]=f2bf(p1.w);
      bfr[kc] = tt;
    }
    const int hcol = ht*16 + r16;
    #pragma unroll
    for (int bs = 0; bs < 4; ++bs) {
      f32x4 acc = {0.f, 0.f, 0.f, 0.f};
      #pragma unroll
      for (int kc = 0; kc < 4; ++kc)
        acc = __builtin_amdgcn_mfma_f32_16x16x32_bf16(afr[bs][kc], bfr[kc], acc, 0, 0, 0);
      // weighted accumulate: D[row=b-local, col=h-local] * wvec[b, hcol]
      #pragma unroll
      for (int i = 0; i < 4; ++i) {
        int b = b0 + bs*16 + quad*4 + i;
        gacc[bs][i] += acc[i] * wvec[b*HDIM + hcol];
      }
    }
  }

  // reduce over the 16 h-columns (lanes sharing quad, differing lane&15)
  #pragma unroll
  for (int bs = 0; bs < 4; ++bs)
    #pragma unroll
    for (int i = 0; i < 4; ++i) {
      float v = gacc[bs][i];
      v += __shfl_xor(v, 1);
      v += __shfl_xor(v, 2);
      v += __shfl_xor(v, 4);
      v += __shfl_xor(v, 8);
      if (r16 == 0) {
        int b = b0 + bs*16 + quad*4 + i;
        if (PHASE == 0) g1out[b*HDIM + kcol] = tanhf(v);
        else            out[b*HDIM + kcol] = v;
      }
    }
}

extern "C" void kernel_launch(void* const* d_in, const int* in_sizes, int n_in,
                              void* d_out, int out_size, void* d_ws, size_t ws_size,
                              hipStream_t stream) {
  const float* h0  = (const float*)d_in[0];
  const float* htt = (const float*)d_in[1];
  const float* msg = (const float*)d_in[2];
  const float* c   = (const float*)d_in[3];
  const float* w1  = (const float*)d_in[4];
  const float* w2  = (const float*)d_in[5];
  const float* w3  = (const float*)d_in[6];
  const float* w4  = (const float*)d_in[7];
  float* out = (float*)d_out;

  short* x3bf = (short*)d_ws;                          // 1024*128*2 = 256 KB
  float* g1   = (float*)((char*)d_ws + 256 * 1024);    // 1024*256*4 = 1 MB

  k_mlp<<<dim3(1024), dim3(128), 0, stream>>>(h0, htt, c, w1, w2, w3, x3bf);
  k_hyper<0><<<dim3(256, 4), dim3(256), 0, stream>>>(x3bf, msg, w4, g1, nullptr);
  k_hyper<1><<<dim3(256, 4), dim3(256), 0, stream>>>(x3bf, g1, w4, nullptr, out);
}

// Round 3
// 277.426 us; speedup vs baseline: 1.0840x; 1.0840x over previous
//
#include <hip/hip_runtime.h>
#include <hip/hip_bf16.h>

#define HDIM 256
#define HPDIM 128

typedef short bf8 __attribute__((ext_vector_type(8)));   // 8 bf16 in 4 VGPRs
typedef float f32x4 __attribute__((ext_vector_type(4)));

__device__ inline unsigned pkbf2(float a, float b) {
  float2 f; f.x = a; f.y = b;
  __hip_bfloat162 h = __float22bfloat162_rn(f);          // v_cvt_pk_bf16_f32 (RNE)
  unsigned u; __builtin_memcpy(&u, &h, 4); return u;
}
__device__ inline unsigned short bfbits(float v) {
  __hip_bfloat16 h = __float2bfloat16(v);
  unsigned short u; __builtin_memcpy(&u, &h, 2); return u;
}
__device__ inline bf8 pack8(float4 a, float4 b) {
  union { bf8 v; unsigned u[4]; } r;
  r.u[0] = pkbf2(a.x, a.y); r.u[1] = pkbf2(a.z, a.w);
  r.u[2] = pkbf2(b.x, b.y); r.u[3] = pkbf2(b.z, b.w);
  return r.v;
}
__device__ inline float fast_tanh(float x) {
  // tanh(x) = 1 - 2/(exp2(x*2*log2 e)+1); exact at +-inf, ~1ulp via v_rcp
  float t = __builtin_expf(x * 2.0f * 1.4426950408889634f * 0.6931471805599453f);
  // NB: expf lowers to v_exp_f32 path; keep simple and robust:
  t = __expf(2.0f * x);
  return 1.0f - 2.0f * __builtin_amdgcn_rcpf(t + 1.0f);
}

// ---------------- Kernel A: front MLP -> x3 (bf16), MFMA version ----------
// grid 16 blocks x 256 thr; block owns 64 b. LDS: hbuf 32K + xa 16K + xb 16K.
__global__ __launch_bounds__(256) void k_mlp(
    const float* __restrict__ h0, const float* __restrict__ htv,
    const float* __restrict__ cp,
    const float* __restrict__ w1, const float* __restrict__ w2,
    const float* __restrict__ w3, short* __restrict__ x3bf) {
  __shared__ char lds[65536];
  char* hbuf = lds;            // 64 x 256 bf16, xor-swizzled 16B blocks
  char* xa   = lds + 32768;    // 64 x 128 bf16
  char* xb   = lds + 49152;    // 64 x 128 bf16
  const int t = threadIdx.x, wave = t >> 6, lane = t & 63;
  const int r16 = lane & 15, quad = lane >> 4;
  const int b0 = blockIdx.x * 64;
  float cc = fminf(fmaxf(cp[0], 0.f), 1.f);

  // stage h = cc*h0 + (1-cc)*ht -> hbuf (bf16)
  for (int it = 0; it < 16; ++it) {
    int flat = it * 1024 + t * 4;
    int row = flat >> 8, col = flat & 255;
    int gi = (b0 + row) * HDIM + col;
    float4 a = *(const float4*)(h0 + gi);
    float4 b = *(const float4*)(htv + gi);
    float4 v; v.x = cc*a.x + (1.f-cc)*b.x; v.y = cc*a.y + (1.f-cc)*b.y;
              v.z = cc*a.z + (1.f-cc)*b.z; v.w = cc*a.w + (1.f-cc)*b.w;
    int kb = col >> 3, half = (col >> 2) & 1;
    uint2 pk; pk.x = pkbf2(v.x, v.y); pk.y = pkbf2(v.z, v.w);
    *(uint2*)(hbuf + row*512 + ((kb ^ (row & 7)) << 4) + half*8) = pk;
  }
  __syncthreads();

  // ---- layer 1: [64 x 256] @ w1^T[256 x 128] -> xa ----
  {
    f32x4 acc[4][2] = {};
    for (int ks = 0; ks < 8; ++ks) {
      bf8 bfr[2];
      #pragma unroll
      for (int nt = 0; nt < 2; ++nt) {
        int p = wave*32 + nt*16 + r16;
        const float* wp = w1 + p*HDIM + ks*32 + quad*8;
        bfr[nt] = pack8(*(const float4*)wp, *(const float4*)(wp + 4));
      }
      #pragma unroll
      for (int mt = 0; mt < 4; ++mt) {
        int row = mt*16 + r16;
        bf8 af = *(bf8*)(hbuf + row*512 + ((((ks*4 + quad)) ^ (row & 7)) << 4));
        #pragma unroll
        for (int nt = 0; nt < 2; ++nt)
          acc[mt][nt] = __builtin_amdgcn_mfma_f32_16x16x32_bf16(af, bfr[nt], acc[mt][nt], 0, 0, 0);
      }
    }
    #pragma unroll
    for (int mt = 0; mt < 4; ++mt)
      #pragma unroll
      for (int nt = 0; nt < 2; ++nt)
        #pragma unroll
        for (int i = 0; i < 4; ++i) {
          int row = mt*16 + quad*4 + i, col = wave*32 + nt*16 + r16;
          *(unsigned short*)(xa + row*256 + (((col >> 3) ^ (row & 7)) << 4) + ((col & 7) << 1))
              = bfbits(fast_tanh(acc[mt][nt][i]));
        }
  }
  __syncthreads();

  // ---- layer 2: xa @ w2^T -> xb ----
  {
    f32x4 acc[4][2] = {};
    for (int ks = 0; ks < 4; ++ks) {
      bf8 bfr[2];
      #pragma unroll
      for (int nt = 0; nt < 2; ++nt) {
        int p = wave*32 + nt*16 + r16;
        const float* wp = w2 + p*HPDIM + ks*32 + quad*8;
        bfr[nt] = pack8(*(const float4*)wp, *(const float4*)(wp + 4));
      }
      #pragma unroll
      for (int mt = 0; mt < 4; ++mt) {
        int row = mt*16 + r16;
        bf8 af = *(bf8*)(xa + row*256 + (((ks*4 + quad) ^ (row & 7)) << 4));
        #pragma unroll
        for (int nt = 0; nt < 2; ++nt)
          acc[mt][nt] = __builtin_amdgcn_mfma_f32_16x16x32_bf16(af, bfr[nt], acc[mt][nt], 0, 0, 0);
      }
    }
    #pragma unroll
    for (int mt = 0; mt < 4; ++mt)
      #pragma unroll
      for (int nt = 0; nt < 2; ++nt)
        #pragma unroll
        for (int i = 0; i < 4; ++i) {
          int row = mt*16 + quad*4 + i, col = wave*32 + nt*16 + r16;
          *(unsigned short*)(xb + row*256 + (((col >> 3) ^ (row & 7)) << 4) + ((col & 7) << 1))
              = bfbits(fast_tanh(acc[mt][nt][i]));
        }
  }
  __syncthreads();

  // ---- layer 3: xb @ w3^T -> xa (reuse) ----
  {
    f32x4 acc[4][2] = {};
    for (int ks = 0; ks < 4; ++ks) {
      bf8 bfr[2];
      #pragma unroll
      for (int nt = 0; nt < 2; ++nt) {
        int p = wave*32 + nt*16 + r16;
        const float* wp = w3 + p*HPDIM + ks*32 + quad*8;
        bfr[nt] = pack8(*(const float4*)wp, *(const float4*)(wp + 4));
      }
      #pragma unroll
      for (int mt = 0; mt < 4; ++mt) {
        int row = mt*16 + r16;
        bf8 af = *(bf8*)(xb + row*256 + (((ks*4 + quad) ^ (row & 7)) << 4));
        #pragma unroll
        for (int nt = 0; nt < 2; ++nt)
          acc[mt][nt] = __builtin_amdgcn_mfma_f32_16x16x32_bf16(af, bfr[nt], acc[mt][nt], 0, 0, 0);
      }
    }
    #pragma unroll
    for (int mt = 0; mt < 4; ++mt)
      #pragma unroll
      for (int nt = 0; nt < 2; ++nt)
        #pragma unroll
        for (int i = 0; i < 4; ++i) {
          int row = mt*16 + quad*4 + i, col = wave*32 + nt*16 + r16;
          *(unsigned short*)(xa + row*256 + (((col >> 3) ^ (row & 7)) << 4) + ((col & 7) << 1))
              = bfbits(fast_tanh(acc[mt][nt][i]));
        }
  }
  __syncthreads();

  // dump xa (un-swizzle) -> x3bf global, coalesced dwordx4
  {
    int row = t >> 2, j = t & 3;
    #pragma unroll
    for (int i = 0; i < 4; ++i) {
      int kb = j*4 + i;
      uint4 d = *(uint4*)(xa + row*256 + ((kb ^ (row & 7)) << 4));
      *(uint4*)(x3bf + (b0 + row)*HPDIM + kb*8) = d;
    }
  }
}

// ---------------- Kernel B/C: fused hypernetwork GEMM --------------------
// PHASE 0: g1[b,kcol] = tanh( sum_h msg[b,h] * (fc4[kcol*256+h,:] . x3[b,:]) )
// PHASE 1: out[b,kcol] =      sum_k g1[b,k]  * (fc4[65536+kcol*256+k,:] . x3[b,:])
// A = fc4 tile (m=h-local), B = x3 (n=b)  =>  D[row=h-local][col=b-local];
// weight wvec[b][h..h+4] is one coalesced dwordx4 per (nt, ht).
// Block: 64 b x one kcol; 4 waves split the 16 ht steps (4 each).
template<int PHASE>
__global__ __launch_bounds__(256) void k_hyper(
    const short* __restrict__ x3bf, const float* __restrict__ wvec,
    const float* __restrict__ fc4, float* __restrict__ outp) {
  __shared__ char lds[65536];          // fc4 slab 256x128 bf16 (swizzled); overlaid by red[16][64] f32
  float* red = (float*)lds;
  const int kcol = blockIdx.x;
  const int b0   = blockIdx.y * 64;
  const int t = threadIdx.x, wave = t >> 6, lane = t & 63;
  const int r16 = lane & 15, quad = lane >> 4;

  // ---- stage fc4 slab (256 rows x 128 f32) -> LDS bf16, swizzled ----
  const float* src = fc4 + ((PHASE ? 65536 : 0) + kcol * 256) * HPDIM;
  #pragma unroll 4
  for (int it = 0; it < 32; ++it) {
    int flat = it * 1024 + t * 4;
    int row = flat >> 7, col = flat & 127;
    float4 v = *(const float4*)(src + flat);
    int kb = col >> 3, half = (col >> 2) & 1;
    uint2 pk; pk.x = pkbf2(v.x, v.y); pk.y = pkbf2(v.z, v.w);
    *(uint2*)(lds + row*256 + ((kb ^ (row & 7)) << 4) + half*8) = pk;
  }

  // ---- x3 B-fragments: [nt 0..3][ks 0..3], held whole kernel ----
  bf8 xf[4][4];
  #pragma unroll
  for (int nt = 0; nt < 4; ++nt)
    #pragma unroll
    for (int ks = 0; ks < 4; ++ks)
      xf[nt][ks] = *(const bf8*)(x3bf + (b0 + nt*16 + r16)*HPDIM + ks*32 + quad*8);

  __syncthreads();

  float gacc[4] = {0.f, 0.f, 0.f, 0.f};
  #pragma unroll
  for (int hti = 0; hti < 4; ++hti) {
    const int ht = wave * 4 + hti;           // this wave's h-tile (16 rows)
    bf8 af[4];
    #pragma unroll
    for (int ks = 0; ks < 4; ++ks) {
      int row = ht*16 + r16;
      af[ks] = *(bf8*)(lds + row*256 + (((ks*4 + quad) ^ (row & 7)) << 4));
    }
    #pragma unroll
    for (int nt = 0; nt < 4; ++nt) {
      f32x4 acc = {};
      #pragma unroll
      for (int ks = 0; ks < 4; ++ks)
        acc = __builtin_amdgcn_mfma_f32_16x16x32_bf16(af[ks], xf[nt][ks], acc, 0, 0, 0);
      float4 w = *(const float4*)(wvec + (b0 + nt*16 + r16)*HDIM + ht*16 + quad*4);
      gacc[nt] += acc[0]*w.x + acc[1]*w.y + acc[2]*w.z + acc[3]*w.w;
    }
  }

  __syncthreads();                            // all slab reads complete
  #pragma unroll
  for (int nt = 0; nt < 4; ++nt)
    red[(wave*4 + quad)*64 + nt*16 + r16] = gacc[nt];
  __syncthreads();

  if (t < 64) {
    float s = 0.f;
    #pragma unroll
    for (int wq = 0; wq < 16; ++wq) s += red[wq*64 + t];
    if (PHASE == 0) outp[(b0 + t)*HDIM + kcol] = fast_tanh(s);
    else            outp[(b0 + t)*HDIM + kcol] = s;
  }
}

extern "C" void kernel_launch(void* const* d_in, const int* in_sizes, int n_in,
                              void* d_out, int out_size, void* d_ws, size_t ws_size,
                              hipStream_t stream) {
  const float* h0  = (const float*)d_in[0];
  const float* htt = (const float*)d_in[1];
  const float* msg = (const float*)d_in[2];
  const float* c   = (const float*)d_in[3];
  const float* w1  = (const float*)d_in[4];
  const float* w2  = (const float*)d_in[5];
  const float* w3  = (const float*)d_in[6];
  const float* w4  = (const float*)d_in[7];
  float* out = (float*)d_out;

  short* x3bf = (short*)d_ws;                          // 1024*128*2 = 256 KB
  float* g1   = (float*)((char*)d_ws + 262144);        // 1024*256*4 = 1 MB

  k_mlp<<<dim3(16), dim3(256), 0, stream>>>(h0, htt, c, w1, w2, w3, x3bf);
  k_hyper<0><<<dim3(256, 16), dim3(256), 0, stream>>>(x3bf, msg, w4, g1);
  k_hyper<1><<<dim3(256, 16), dim3(256), 0, stream>>>(x3bf, g1, w4, out);
}

// Round 4
// 191.908 us; speedup vs baseline: 1.5670x; 1.4456x over previous
//
#include <hip/hip_runtime.h>
#include <hip/hip_bf16.h>

#define HDIM 256
#define HPDIM 128

typedef short bf8 __attribute__((ext_vector_type(8)));   // 8 bf16 in 4 VGPRs
typedef float f32x4 __attribute__((ext_vector_type(4)));

__device__ inline unsigned pkbf2(float a, float b) {
  float2 f; f.x = a; f.y = b;
  __hip_bfloat162 h = __float22bfloat162_rn(f);          // v_cvt_pk_bf16_f32 (RNE)
  unsigned u; __builtin_memcpy(&u, &h, 4); return u;
}
__device__ inline unsigned short bfbits(float v) {
  __hip_bfloat16 h = __float2bfloat16(v);
  unsigned short u; __builtin_memcpy(&u, &h, 2); return u;
}
__device__ inline uint4 pack8u(float4 a, float4 b) {
  uint4 r;
  r.x = pkbf2(a.x, a.y); r.y = pkbf2(a.z, a.w);
  r.z = pkbf2(b.x, b.y); r.w = pkbf2(b.z, b.w);
  return r;
}
__device__ inline float fast_tanh(float x) {
  float t = __expf(2.0f * x);                 // inf/0 at extremes -> +-1 exact
  return 1.0f - 2.0f * __builtin_amdgcn_rcpf(t + 1.0f);
}

// ---------------- Kernel A: front MLP -> x3 (bf16) -----------------------
// grid 64 x 256 thr; block owns 16 b. Weights staged coalesced into a
// shared 64KB wbuf (reused per layer); frags read from LDS (no 16-line
// global gathers). LDS 80KB -> 2 blocks/CU.
__global__ __launch_bounds__(256) void k_mlp(
    const float* __restrict__ h0, const float* __restrict__ htv,
    const float* __restrict__ cp,
    const float* __restrict__ w1, const float* __restrict__ w2,
    const float* __restrict__ w3, short* __restrict__ x3bf) {
  __shared__ char wbuf[65536];   // layer1: 128 rows x 256 bf16 (512B/row); layers2/3: 128 x 128 (256B/row)
  __shared__ char hbuf[8192];    // 16 x 256 bf16, swizzled
  __shared__ char xa[4096];      // 16 x 128 bf16, swizzled
  __shared__ char xb[4096];
  const int t = threadIdx.x, wave = t >> 6, lane = t & 63;
  const int r16 = lane & 15, quad = lane >> 4;
  const int b0 = blockIdx.x * 16;
  const float cc = fminf(fmaxf(cp[0], 0.f), 1.f);

  // stage h = cc*h0+(1-cc)*ht (16x256 f32), 8 floats/thread/iter
  #pragma unroll
  for (int it = 0; it < 2; ++it) {
    int flat = it * 2048 + t * 8;
    int row = flat >> 8, col = flat & 255, kb = col >> 3;
    int gi = (b0 + row) * HDIM + col;
    float4 a = *(const float4*)(h0 + gi);
    float4 b = *(const float4*)(htv + gi);
    float4 va, vb;
    va.x = cc*a.x + (1.f-cc)*b.x; va.y = cc*a.y + (1.f-cc)*b.y;
    va.z = cc*a.z + (1.f-cc)*b.z; va.w = cc*a.w + (1.f-cc)*b.w;
    a = *(const float4*)(h0 + gi + 4); b = *(const float4*)(htv + gi + 4);
    vb.x = cc*a.x + (1.f-cc)*b.x; vb.y = cc*a.y + (1.f-cc)*b.y;
    vb.z = cc*a.z + (1.f-cc)*b.z; vb.w = cc*a.w + (1.f-cc)*b.w;
    *(uint4*)(hbuf + row*512 + ((kb ^ (row & 7)) << 4)) = pack8u(va, vb);
  }
  // stage w1 (128x256 f32)
  #pragma unroll 4
  for (int it = 0; it < 16; ++it) {
    int flat = it * 2048 + t * 8;
    int row = flat >> 8, col = flat & 255, kb = col >> 3;
    float4 a = *(const float4*)(w1 + flat);
    float4 b = *(const float4*)(w1 + flat + 4);
    *(uint4*)(wbuf + row*512 + ((kb ^ (row & 7)) << 4)) = pack8u(a, b);
  }
  __syncthreads();

  // layer 1: [16 x 256] @ w1^T -> xa (tanh)
  {
    f32x4 acc[2] = {};
    #pragma unroll
    for (int ks = 0; ks < 8; ++ks) {
      bf8 af = *(bf8*)(hbuf + r16*512 + (((ks*4 + quad) ^ (r16 & 7)) << 4));
      #pragma unroll
      for (int nt = 0; nt < 2; ++nt) {
        int p = wave*32 + nt*16 + r16;
        bf8 bf_ = *(bf8*)(wbuf + p*512 + (((ks*4 + quad) ^ (p & 7)) << 4));
        acc[nt] = __builtin_amdgcn_mfma_f32_16x16x32_bf16(af, bf_, acc[nt], 0, 0, 0);
      }
    }
    #pragma unroll
    for (int nt = 0; nt < 2; ++nt)
      #pragma unroll
      for (int i = 0; i < 4; ++i) {
        int row = quad*4 + i, col = wave*32 + nt*16 + r16;
        *(unsigned short*)(xa + row*256 + (((col >> 3) ^ (row & 7)) << 4) + ((col & 7) << 1))
            = bfbits(fast_tanh(acc[nt][i]));
      }
  }
  __syncthreads();
  // stage w2 (128x128)
  #pragma unroll 4
  for (int it = 0; it < 8; ++it) {
    int flat = it * 2048 + t * 8;
    int row = flat >> 7, kb = t & 15;
    float4 a = *(const float4*)(w2 + flat);
    float4 b = *(const float4*)(w2 + flat + 4);
    *(uint4*)(wbuf + row*256 + ((kb ^ (row & 7)) << 4)) = pack8u(a, b);
  }
  __syncthreads();
  // layer 2: xa @ w2^T -> xb
  {
    f32x4 acc[2] = {};
    #pragma unroll
    for (int ks = 0; ks < 4; ++ks) {
      bf8 af = *(bf8*)(xa + r16*256 + (((ks*4 + quad) ^ (r16 & 7)) << 4));
      #pragma unroll
      for (int nt = 0; nt < 2; ++nt) {
        int p = wave*32 + nt*16 + r16;
        bf8 bf_ = *(bf8*)(wbuf + p*256 + (((ks*4 + quad) ^ (p & 7)) << 4));
        acc[nt] = __builtin_amdgcn_mfma_f32_16x16x32_bf16(af, bf_, acc[nt], 0, 0, 0);
      }
    }
    #pragma unroll
    for (int nt = 0; nt < 2; ++nt)
      #pragma unroll
      for (int i = 0; i < 4; ++i) {
        int row = quad*4 + i, col = wave*32 + nt*16 + r16;
        *(unsigned short*)(xb + row*256 + (((col >> 3) ^ (row & 7)) << 4) + ((col & 7) << 1))
            = bfbits(fast_tanh(acc[nt][i]));
      }
  }
  __syncthreads();
  // stage w3 (128x128)
  #pragma unroll 4
  for (int it = 0; it < 8; ++it) {
    int flat = it * 2048 + t * 8;
    int row = flat >> 7, kb = t & 15;
    float4 a = *(const float4*)(w3 + flat);
    float4 b = *(const float4*)(w3 + flat + 4);
    *(uint4*)(wbuf + row*256 + ((kb ^ (row & 7)) << 4)) = pack8u(a, b);
  }
  __syncthreads();
  // layer 3: xb @ w3^T -> xa
  {
    f32x4 acc[2] = {};
    #pragma unroll
    for (int ks = 0; ks < 4; ++ks) {
      bf8 af = *(bf8*)(xb + r16*256 + (((ks*4 + quad) ^ (r16 & 7)) << 4));
      #pragma unroll
      for (int nt = 0; nt < 2; ++nt) {
        int p = wave*32 + nt*16 + r16;
        bf8 bf_ = *(bf8*)(wbuf + p*256 + (((ks*4 + quad) ^ (p & 7)) << 4));
        acc[nt] = __builtin_amdgcn_mfma_f32_16x16x32_bf16(af, bf_, acc[nt], 0, 0, 0);
      }
    }
    #pragma unroll
    for (int nt = 0; nt < 2; ++nt)
      #pragma unroll
      for (int i = 0; i < 4; ++i) {
        int row = quad*4 + i, col = wave*32 + nt*16 + r16;
        *(unsigned short*)(xa + row*256 + (((col >> 3) ^ (row & 7)) << 4) + ((col & 7) << 1))
            = bfbits(fast_tanh(acc[nt][i]));
      }
  }
  __syncthreads();
  // dump xa -> x3bf, coalesced uint4
  {
    int row = t >> 4, kb = t & 15;
    uint4 d = *(uint4*)(xa + row*256 + ((kb ^ (row & 7)) << 4));
    *(uint4*)(x3bf + (b0 + row)*HPDIM + kb*8) = d;
  }
}

// ---------------- Kernel B/C: fused hypernetwork GEMM --------------------
// PHASE 0: g1[b,kcol] = tanh( sum_h msg[b,h] * (fc4[kcol*256+h,:] . x3[b,:]) )
// PHASE 1: out[b,kcol] =      sum_k g1[b,k]  * (fc4[65536+kcol*256+k,:] . x3[b,:])
// Block: 1 kcol x 512 b (grid 256 x 2). Slab (256x128) staged once in LDS;
// waves split b (64 each), 2 iterations of 256 b -> only ONE barrier.
// A = slab (m = h-local), B = x3 (n = b) => D[row=h-local][col=b-local].
// h-reduction: per-lane over (ht,i), then shfl_xor over quad. No LDS reduce.
template<int PHASE>
__global__ __launch_bounds__(256) void k_hyper(
    const short* __restrict__ x3bf, const float* __restrict__ wvec,
    const float* __restrict__ fc4, float* __restrict__ outp) {
  __shared__ char lds[65536];          // 256 rows x 128 bf16, xor-swizzled 16B blocks
  const int kcol = blockIdx.x;
  const int t = threadIdx.x, wave = t >> 6, lane = t & 63;
  const int r16 = lane & 15, quad = lane >> 4;

  // ---- stage fc4 slab (256x128 f32 -> bf16), one ds_write_b128/thread/iter
  const float* src = fc4 + ((size_t)(PHASE ? 65536 : 0) + (size_t)kcol * 256) * HPDIM;
  #pragma unroll 4
  for (int it = 0; it < 16; ++it) {
    int flat = it * 2048 + t * 8;
    int row = flat >> 7, kb = t & 15;
    float4 a = *(const float4*)(src + flat);
    float4 b = *(const float4*)(src + flat + 4);
    *(uint4*)(lds + row*256 + ((kb ^ (row & 7)) << 4)) = pack8u(a, b);
  }
  __syncthreads();

  const int ybase = blockIdx.y * 512;
  #pragma unroll 1
  for (int iter = 0; iter < 2; ++iter) {
    const int bw = ybase + iter*256 + wave*64;   // this wave's 64 b
    bf8 xf[4][4];
    #pragma unroll
    for (int nt = 0; nt < 4; ++nt)
      #pragma unroll
      for (int ks = 0; ks < 4; ++ks)
        xf[nt][ks] = *(const bf8*)(x3bf + (bw + nt*16 + r16)*HPDIM + ks*32 + quad*8);

    float gacc[4] = {0.f, 0.f, 0.f, 0.f};
    #pragma unroll 2
    for (int ht = 0; ht < 16; ++ht) {
      bf8 af[4];
      const int row = ht*16 + r16;
      #pragma unroll
      for (int ks = 0; ks < 4; ++ks)
        af[ks] = *(bf8*)(lds + row*256 + (((ks*4 + quad) ^ (row & 7)) << 4));
      #pragma unroll
      for (int nt = 0; nt < 4; ++nt) {
        f32x4 acc = {};
        #pragma unroll
        for (int ks = 0; ks < 4; ++ks)
          acc = __builtin_amdgcn_mfma_f32_16x16x32_bf16(af[ks], xf[nt][ks], acc, 0, 0, 0);
        float4 w = *(const float4*)(wvec + (bw + nt*16 + r16)*HDIM + ht*16 + quad*4);
        gacc[nt] += acc[0]*w.x + acc[1]*w.y + acc[2]*w.z + acc[3]*w.w;
      }
    }
    #pragma unroll
    for (int nt = 0; nt < 4; ++nt) {
      float v = gacc[nt];
      v += __shfl_xor(v, 16);
      v += __shfl_xor(v, 32);
      if (quad == 0) {
        int b = bw + nt*16 + r16;
        outp[b*HDIM + kcol] = (PHASE == 0) ? fast_tanh(v) : v;
      }
    }
  }
}

extern "C" void kernel_launch(void* const* d_in, const int* in_sizes, int n_in,
                              void* d_out, int out_size, void* d_ws, size_t ws_size,
                              hipStream_t stream) {
  const float* h0  = (const float*)d_in[0];
  const float* htt = (const float*)d_in[1];
  const float* msg = (const float*)d_in[2];
  const float* c   = (const float*)d_in[3];
  const float* w1  = (const float*)d_in[4];
  const float* w2  = (const float*)d_in[5];
  const float* w3  = (const float*)d_in[6];
  const float* w4  = (const float*)d_in[7];
  float* out = (float*)d_out;

  short* x3bf = (short*)d_ws;                          // 1024*128*2 = 256 KB
  float* g1   = (float*)((char*)d_ws + 262144);        // 1024*256*4 = 1 MB

  k_mlp<<<dim3(64), dim3(256), 0, stream>>>(h0, htt, c, w1, w2, w3, x3bf);
  k_hyper<0><<<dim3(256, 2), dim3(256), 0, stream>>>(x3bf, msg, w4, g1);
  k_hyper<1><<<dim3(256, 2), dim3(256), 0, stream>>>(x3bf, g1, w4, out);
}